// Round 3
// baseline (183.961 us; speedup 1.0000x reference)
//
#include <hip/hip_runtime.h>
#include <math.h>

#define NCLUST 512
#define DPER 32
#define NFEAT 1024
#define NSAMP (NCLUST * DPER)   // 16384
#define ALPHA_C 1.0f
#define EPS_C 1e-8f
#define MARGIN_C 0.25f

#define GBM 128
#define GBN 128
#define GBK 32
#define NCHUNK 8   // 512 cols / 64-col wave chunks

typedef __attribute__((ext_vector_type(4))) float f32x4;
typedef __attribute__((ext_vector_type(8))) _Float16 f16x8;

__device__ __forceinline__ ushort f2h(float f) {
  _Float16 h = (_Float16)f;
  return __builtin_bit_cast(ushort, h);
}

__device__ __forceinline__ void gload16(const ushort* g, ushort* l) {
  __builtin_amdgcn_global_load_lds(
      (const __attribute__((address_space(1))) unsigned int*)g,
      (__attribute__((address_space(3))) unsigned int*)l, 16, 0, 0);
}

// ---------------- Kernel A: means, c2, ccls, Bf16 ----------------
__global__ __launch_bounds__(256) void k_means(const float* __restrict__ inp,
                                               const int* __restrict__ target,
                                               float* __restrict__ means,
                                               ushort* __restrict__ Bf16,
                                               float* __restrict__ c2,
                                               int* __restrict__ ccls) {
  const int m = blockIdx.x;
  const int t = threadIdx.x;      // 256 threads, 4 floats each
  const float* base = inp + (size_t)m * DPER * NFEAT + t * 4;
  float4 s = make_float4(0.f, 0.f, 0.f, 0.f);
  #pragma unroll 8
  for (int d = 0; d < DPER; ++d) {
    float4 v = *(const float4*)(base + (size_t)d * NFEAT);
    s.x += v.x; s.y += v.y; s.z += v.z; s.w += v.w;
  }
  const float inv = 1.0f / 32.0f;
  s.x *= inv; s.y *= inv; s.z *= inv; s.w *= inv;
  *(float4*)(means + (size_t)m * NFEAT + t * 4) = s;
  uint2 hw;
  hw.x = (unsigned)f2h(s.x) | ((unsigned)f2h(s.y) << 16);
  hw.y = (unsigned)f2h(s.z) | ((unsigned)f2h(s.w) << 16);
  *(uint2*)&Bf16[(size_t)m * NFEAT + t * 4] = hw;

  float sq = s.x * s.x + s.y * s.y + s.z * s.z + s.w * s.w;
  __shared__ float red[4];
  #pragma unroll
  for (int off = 32; off > 0; off >>= 1) sq += __shfl_down(sq, off);
  if ((t & 63) == 0) red[t >> 6] = sq;
  __syncthreads();
  if (t == 0) {
    c2[m] = red[0] + red[1] + red[2] + red[3];
    ccls[m] = target[m * DPER];
  }
}

// ---------------- Kernel B: r2, intra, Af16 ----------------
__global__ __launch_bounds__(256) void k_rows(const float* __restrict__ inp,
                                              const float* __restrict__ means,
                                              const float* __restrict__ c2,
                                              float* __restrict__ r2,
                                              float* __restrict__ intra,
                                              ushort* __restrict__ Af16) {
  const int row = blockIdx.x * 4 + (threadIdx.x >> 6);
  const int lane = threadIdx.x & 63;
  const int cl = row >> 5;
  const float4* ip = (const float4*)(inp + (size_t)row * NFEAT);
  const float4* mp = (const float4*)(means + (size_t)cl * NFEAT);
  float rr = 0.f, dd = 0.f;
  #pragma unroll
  for (int j = 0; j < 4; ++j) {
    float4 v = ip[lane + 64 * j];
    float4 mv = mp[lane + 64 * j];
    rr += v.x * v.x + v.y * v.y + v.z * v.z + v.w * v.w;
    dd += v.x * mv.x + v.y * mv.y + v.z * mv.z + v.w * mv.w;
    uint2 hw;
    hw.x = (unsigned)f2h(v.x) | ((unsigned)f2h(v.y) << 16);
    hw.y = (unsigned)f2h(v.z) | ((unsigned)f2h(v.w) << 16);
    *(uint2*)&Af16[(size_t)row * NFEAT + (lane + 64 * j) * 4] = hw;
  }
  #pragma unroll
  for (int off = 32; off > 0; off >>= 1) {
    rr += __shfl_down(rr, off);
    dd += __shfl_down(dd, off);
  }
  if (lane == 0) {
    r2[row] = rr;
    intra[row] = rr + c2[cl] - 2.0f * dd;
  }
}

// ---------------- Kernel D: variance -> var_norm ----------------
__global__ __launch_bounds__(256) void k_var(const float* __restrict__ intra,
                                             float* __restrict__ vn) {
  const int t = threadIdx.x;
  float s = 0.f;
  for (int i = t; i < NSAMP; i += 256) s += intra[i];
  __shared__ float red[4];
  #pragma unroll
  for (int off = 32; off > 0; off >>= 1) s += __shfl_down(s, off);
  if ((t & 63) == 0) red[t >> 6] = s;
  __syncthreads();
  if (t == 0) {
    float tot = red[0] + red[1] + red[2] + red[3];
    float var = tot / (float)(NSAMP - 1);
    vn[0] = -1.0f / (2.0f * var * var);
  }
}

// ---------------- Kernel E: f16 MFMA GEMM (m97 template) + epilogue ----------
// 128x128x32 tile, 4 waves (2x2), wave tile 64x64, global_load_lds staging,
// XOR chunk swizzle. Grid 512 = 128 rowblks x 4 colblks, XCD-swizzled.
__global__ __launch_bounds__(256, 3) void k_gemm(
    const ushort* __restrict__ Af16, const ushort* __restrict__ Bf16,
    const float* __restrict__ c2, const float* __restrict__ r2,
    const float* __restrict__ vnp, const int* __restrict__ ccls,
    const int* __restrict__ target,
    float* __restrict__ den_p, float* __restrict__ minv_p,
    float* __restrict__ minv2_p, float* __restrict__ minc_p) {
  __shared__ ushort As[GBM * GBK];   // 8 KiB, [row][chunk^ (row&3)]
  __shared__ ushort Bs[GBN * GBK];   // 8 KiB
  const int t = threadIdx.x;
  const int l = t & 63, w = t >> 6;
  const int wg = (blockIdx.x & 7) * 64 + (blockIdx.x >> 3);  // bijective (512%8==0)
  const int rowblk = wg >> 2, colblk = wg & 3;
  const int row0 = rowblk * GBM, c0 = colblk * GBN;
  const int wr = w >> 1, wc = w & 1;

  // staging: wave w, instr i in {0,1}: 16 rows each; lane -> (row=l>>2, chunk=l&3)
  const int sR = l >> 2;
  const int sg = (l & 3) ^ (sR & 3);      // pre-swizzled source chunk
  const ushort* srcA0 = Af16 + (size_t)(row0 + w * 32 + sR) * NFEAT + sg * 8;
  const ushort* srcA1 = srcA0 + 16 * NFEAT;
  const ushort* srcB0 = Bf16 + (size_t)(c0 + w * 32 + sR) * NFEAT + sg * 8;
  const ushort* srcB1 = srcB0 + 16 * NFEAT;
  ushort* ldsA0 = As + w * 32 * GBK;
  ushort* ldsA1 = ldsA0 + 16 * GBK;
  ushort* ldsB0 = Bs + w * 32 * GBK;
  ushort* ldsB1 = ldsB0 + 16 * GBK;

  const int fr = l & 15, fq = l >> 4;
  const int ch = ((fq ^ (fr & 3)) * 8);   // swizzled chunk offset (ushorts)

  f32x4 acc[4][4];
  #pragma unroll
  for (int i = 0; i < 4; ++i)
    #pragma unroll
    for (int j = 0; j < 4; ++j) acc[i][j] = (f32x4){0.f, 0.f, 0.f, 0.f};

  for (int ks = 0; ks < NFEAT / GBK; ++ks) {
    __syncthreads();
    gload16(srcA0, ldsA0); gload16(srcA1, ldsA1);
    gload16(srcB0, ldsB0); gload16(srcB1, ldsB1);
    srcA0 += GBK; srcA1 += GBK; srcB0 += GBK; srcB1 += GBK;
    __syncthreads();
    f16x8 a[4], b[4];
    #pragma unroll
    for (int i = 0; i < 4; ++i)
      a[i] = *(const f16x8*)&As[(wr * 64 + i * 16 + fr) * GBK + ch];
    #pragma unroll
    for (int j = 0; j < 4; ++j)
      b[j] = *(const f16x8*)&Bs[(wc * 64 + j * 16 + fr) * GBK + ch];
    #pragma unroll
    for (int i = 0; i < 4; ++i)
      #pragma unroll
      for (int j = 0; j < 4; ++j)
        acc[i][j] = __builtin_amdgcn_mfma_f32_16x16x32_f16(a[i], b[j], acc[i][j], 0, 0, 0);
  }

  // ---- fused epilogue: per 64-col chunk: den, best, second-best, argmin ----
  const float vn = vnp[0];
  float c2j[4]; int clsj[4];
  #pragma unroll
  for (int j = 0; j < 4; ++j) {
    const int c = c0 + wc * 64 + j * 16 + fr;
    c2j[j] = c2[c];
    clsj[j] = ccls[c];
  }
  const int colchunk = colblk * 2 + wc;
  #pragma unroll
  for (int i = 0; i < 4; ++i) {
    const int rbase = row0 + wr * 64 + i * 16 + fq * 4;
    float r2v[4]; int tg[4];
    #pragma unroll
    for (int v = 0; v < 4; ++v) { r2v[v] = r2[rbase + v]; tg[v] = target[rbase + v]; }
    #pragma unroll
    for (int v = 0; v < 4; ++v) {
      float den = 0.f, bv = 3.4e38f, bv2 = 3.4e38f;
      int bc = 1 << 30;
      #pragma unroll
      for (int j = 0; j < 4; ++j) {
        const float cost = r2v[v] + c2j[j] - 2.0f * acc[i][j][v];
        if (clsj[j] != tg[v]) den += __expf(vn * cost);
        if (cost < bv) { bv2 = bv; bv = cost; bc = c0 + wc * 64 + j * 16 + fr; }
        else if (cost < bv2) { bv2 = cost; }
      }
      #pragma unroll
      for (int off = 1; off < 16; off <<= 1) {
        den += __shfl_xor(den, off);
        const float ov = __shfl_xor(bv, off);
        const float ov2 = __shfl_xor(bv2, off);
        const int oc = __shfl_xor(bc, off);
        const float nb2 = fminf(fminf(bv2, ov2), fmaxf(bv, ov));
        if (ov < bv || (ov == bv && oc < bc)) { bv = ov; bc = oc; }
        bv2 = nb2;
      }
      if (fr == 0) {
        const int idx = colchunk * NSAMP + rbase + v;
        den_p[idx] = den;
        minv_p[idx] = bv;
        minv2_p[idx] = bv2;
        minc_p[idx] = (float)bc;
      }
    }
  }
}

// ---------------- Kernel F2: combine partials; margin flag ----------------
__global__ __launch_bounds__(256) void k_fin2(const float* __restrict__ den_p,
                                              const float* __restrict__ minv_p,
                                              const float* __restrict__ minv2_p,
                                              const float* __restrict__ minc_p,
                                              const float* __restrict__ intra,
                                              const float* __restrict__ vnp,
                                              float* __restrict__ losses,
                                              float* __restrict__ preds,
                                              int* __restrict__ flag) {
  const int row = blockIdx.x * 256 + threadIdx.x;
  float den = 0.f, bv = 3.4e38f, bv2 = 3.4e38f, bc = 0.f;
  #pragma unroll
  for (int k = 0; k < NCHUNK; ++k) {
    den += den_p[k * NSAMP + row];
    const float v = minv_p[k * NSAMP + row];
    const float v2 = minv2_p[k * NSAMP + row];
    const float c = minc_p[k * NSAMP + row];
    const float nb2 = fminf(fminf(bv2, v2), fmaxf(bv, v));
    if (v < bv) { bv = v; bc = c; }   // ascending chunk -> first (lowest col) wins ties
    bv2 = nb2;
  }
  const float num = expf(vnp[0] * intra[row] - ALPHA_C);
  const float ratio = num / (den + EPS_C) + EPS_C;
  float loss = -logf(ratio);
  losses[row] = loss > 0.f ? loss : 0.f;
  preds[row] = bc;
  flag[row] = (bv2 - bv < MARGIN_C) ? 1 : 0;
}

// ---------------- Kernel G: exact fp32 argmin fixup for marginal rows -------
__global__ __launch_bounds__(256) void k_fix(const float* __restrict__ inp,
                                             const float* __restrict__ means,
                                             const float* __restrict__ c2,
                                             const float* __restrict__ r2,
                                             const int* __restrict__ flag,
                                             float* __restrict__ preds) {
  __shared__ float rbuf[NFEAT];
  __shared__ float redv[4];
  __shared__ int redc[4];
  const int t = threadIdx.x;
  const int l = t & 63, w = t >> 6;
  for (int row = blockIdx.x; row < NSAMP; row += gridDim.x) {
    if (!flag[row]) continue;
    for (int k = t; k < NFEAT; k += 256) rbuf[k] = inp[(size_t)row * NFEAT + k];
    __syncthreads();
    const float r2v = r2[row];
    float bv = 3.4e38f; int bc = 1 << 30;
    for (int c = t; c < NCLUST; c += 256) {
      const float4* mp = (const float4*)(means + (size_t)c * NFEAT);
      float dot = 0.f;
      #pragma unroll 8
      for (int k = 0; k < NFEAT / 4; ++k) {
        const float4 m4 = mp[k];
        dot += rbuf[k * 4 + 0] * m4.x + rbuf[k * 4 + 1] * m4.y +
               rbuf[k * 4 + 2] * m4.z + rbuf[k * 4 + 3] * m4.w;
      }
      const float cost = r2v + c2[c] - 2.0f * dot;
      if (cost < bv) { bv = cost; bc = c; }   // ascending c: strict < keeps first
    }
    #pragma unroll
    for (int off = 1; off < 64; off <<= 1) {
      const float ov = __shfl_xor(bv, off);
      const int oc = __shfl_xor(bc, off);
      if (ov < bv || (ov == bv && oc < bc)) { bv = ov; bc = oc; }
    }
    if (l == 0) { redv[w] = bv; redc[w] = bc; }
    __syncthreads();
    if (t == 0) {
      float fbv = redv[0]; int fbc = redc[0];
      #pragma unroll
      for (int k = 1; k < 4; ++k) {
        if (redv[k] < fbv || (redv[k] == fbv && redc[k] < fbc)) { fbv = redv[k]; fbc = redc[k]; }
      }
      preds[row] = (float)fbc;
    }
    __syncthreads();
  }
}

// ---------------- Kernel F: total_loss + acc (deterministic) ----------------
__global__ __launch_bounds__(256) void k_final(const float* __restrict__ losses,
                                               const float* __restrict__ preds,
                                               float* __restrict__ out) {
  const int t = threadIdx.x;
  float s = 0.f, cnt = 0.f;
  for (int i = t; i < NSAMP; i += 256) {
    s += losses[i];
    int p = (int)preds[i];
    cnt += (p == (i >> 5)) ? 1.f : 0.f;
  }
  __shared__ float redS[4], redC[4];
  #pragma unroll
  for (int off = 32; off > 0; off >>= 1) {
    s += __shfl_down(s, off);
    cnt += __shfl_down(cnt, off);
  }
  if ((t & 63) == 0) { redS[t >> 6] = s; redC[t >> 6] = cnt; }
  __syncthreads();
  if (t == 0) {
    out[0] = (redS[0] + redS[1] + redS[2] + redS[3]) / (float)NSAMP;
    out[1 + 2 * NSAMP] = (redC[0] + redC[1] + redC[2] + redC[3]) / (float)NSAMP;
  }
}

extern "C" void kernel_launch(void* const* d_in, const int* in_sizes, int n_in,
                              void* d_out, int out_size, void* d_ws, size_t ws_size,
                              hipStream_t stream) {
  const float* inp = (const float*)d_in[0];
  const int* target = (const int*)d_in[1];
  float* out = (float*)d_out;

  ushort* Af16 = (ushort*)d_ws;                        // 16384*1024 f16 (32 MiB)
  ushort* Bf16 = Af16 + (size_t)NSAMP * NFEAT;         // 512*1024 f16 (1 MiB)
  float* means = (float*)(Bf16 + (size_t)NCLUST * NFEAT);  // 512*1024 f32
  float* c2 = means + (size_t)NCLUST * NFEAT;          // 512
  float* r2 = c2 + NCLUST;                             // 16384
  float* intra = r2 + NSAMP;                           // 16384
  float* vn = intra + NSAMP;                           // 1
  int* ccls = (int*)(vn + 1);                          // 512
  float* den_p = (float*)(ccls + NCLUST);              // 8*16384
  float* minv_p = den_p + NCHUNK * NSAMP;              // 8*16384
  float* minv2_p = minv_p + NCHUNK * NSAMP;            // 8*16384
  float* minc_p = minv2_p + NCHUNK * NSAMP;            // 8*16384
  int* flag = (int*)(minc_p + NCHUNK * NSAMP);         // 16384

  float* losses = out + 1;
  float* preds = out + 1 + NSAMP;

  hipLaunchKernelGGL(k_means, dim3(NCLUST), dim3(256), 0, stream,
                     inp, target, means, Bf16, c2, ccls);
  hipLaunchKernelGGL(k_rows, dim3(NSAMP / 4), dim3(256), 0, stream,
                     inp, means, c2, r2, intra, Af16);
  hipLaunchKernelGGL(k_var, dim3(1), dim3(256), 0, stream, intra, vn);
  hipLaunchKernelGGL(k_gemm, dim3(512), dim3(256), 0, stream,
                     Af16, Bf16, c2, r2, vn, ccls, target,
                     den_p, minv_p, minv2_p, minc_p);
  hipLaunchKernelGGL(k_fin2, dim3(NSAMP / 256), dim3(256), 0, stream,
                     den_p, minv_p, minv2_p, minc_p, intra, vn, losses, preds, flag);
  hipLaunchKernelGGL(k_fix, dim3(256), dim3(256), 0, stream,
                     inp, means, c2, r2, flag, preds);
  hipLaunchKernelGGL(k_final, dim3(1), dim3(256), 0, stream, losses, preds, out);
}

// Round 5
// 172.098 us; speedup vs baseline: 1.0689x; 1.0689x over previous
//
#include <hip/hip_runtime.h>
#include <math.h>

#define NCLUST 512
#define DPER 32
#define NFEAT 1024
#define NSAMP (NCLUST * DPER)   // 16384
#define ALPHA_C 1.0f
#define EPS_C 1e-8f
#define MARGIN_C 0.25f

#define GBM 128
#define GBN 128
#define GBK 32
#define NCHUNK 8   // 512 cols / 64-col wave chunks

typedef __attribute__((ext_vector_type(4))) float f32x4;
typedef __attribute__((ext_vector_type(8))) _Float16 f16x8;

__device__ __forceinline__ unsigned f2h(float f) {
  _Float16 h = (_Float16)f;
  return (unsigned)__builtin_bit_cast(ushort, h);
}

__device__ __forceinline__ void gload16(const ushort* g, ushort* l) {
  __builtin_amdgcn_global_load_lds(
      (const __attribute__((address_space(1))) unsigned int*)g,
      (__attribute__((address_space(3))) unsigned int*)l, 16, 0, 0);
}

// ---------------- Kernel PRE: means, c2, ccls, Bf16, Af16, r2, intra --------
// Block = cluster. Pass 1: stream 32x1024 block (HBM), accumulate mean + r2,
// write Af16. Pass 2: re-read (L2-hot) for intra dot with mean.
__global__ __launch_bounds__(256) void k_pre(const float* __restrict__ inp,
                                             const int* __restrict__ target,
                                             float* __restrict__ means,
                                             ushort* __restrict__ Bf16,
                                             ushort* __restrict__ Af16,
                                             float* __restrict__ c2,
                                             float* __restrict__ r2,
                                             float* __restrict__ intra,
                                             int* __restrict__ ccls,
                                             int* __restrict__ wcount) {
  const int m = blockIdx.x;
  const int t = threadIdx.x;
  const int w = t >> 6, l = t & 63;
  __shared__ float redA[DPER][4];
  __shared__ float redB[DPER][4];
  __shared__ float red4[4];
  __shared__ float c2s;
  const float* base = inp + (size_t)m * DPER * NFEAT + t * 4;
  ushort* abase = Af16 + (size_t)m * DPER * NFEAT + t * 4;

  float sx = 0.f, sy = 0.f, sz = 0.f, sw = 0.f;
  for (int d = 0; d < DPER; ++d) {
    float4 v = *(const float4*)(base + (size_t)d * NFEAT);
    sx += v.x; sy += v.y; sz += v.z; sw += v.w;
    uint2 hw;
    hw.x = f2h(v.x) | (f2h(v.y) << 16);
    hw.y = f2h(v.z) | (f2h(v.w) << 16);
    *(uint2*)(abase + (size_t)d * NFEAT) = hw;
    float p = v.x * v.x + v.y * v.y + v.z * v.z + v.w * v.w;
    #pragma unroll
    for (int off = 32; off; off >>= 1) p += __shfl_down(p, off);
    if (l == 0) redA[d][w] = p;
  }
  // mean of this cluster (4 cols per thread)
  const float inv = 1.0f / 32.0f;
  sx *= inv; sy *= inv; sz *= inv; sw *= inv;
  *(float4*)(means + (size_t)m * NFEAT + t * 4) = make_float4(sx, sy, sz, sw);
  uint2 bw;
  bw.x = f2h(sx) | (f2h(sy) << 16);
  bw.y = f2h(sz) | (f2h(sw) << 16);
  *(uint2*)&Bf16[(size_t)m * NFEAT + t * 4] = bw;
  float sq = sx * sx + sy * sy + sz * sz + sw * sw;
  #pragma unroll
  for (int off = 32; off; off >>= 1) sq += __shfl_down(sq, off);
  if (l == 0) red4[w] = sq;
  __syncthreads();
  float rr = 0.f;
  if (t < DPER) {
    rr = redA[t][0] + redA[t][1] + redA[t][2] + redA[t][3];
    r2[m * DPER + t] = rr;
  }
  if (t == 0) {
    float cc = red4[0] + red4[1] + red4[2] + red4[3];
    c2s = cc;
    c2[m] = cc;
    ccls[m] = target[m * DPER];
    if (m == 0) *wcount = 0;   // reset worklist counter each call
  }
  __syncthreads();
  const float c2v = c2s;
  // pass 2: intra dot (L2-hot re-read)
  for (int d = 0; d < DPER; ++d) {
    float4 v = *(const float4*)(base + (size_t)d * NFEAT);
    float p = v.x * sx + v.y * sy + v.z * sz + v.w * sw;
    #pragma unroll
    for (int off = 32; off; off >>= 1) p += __shfl_down(p, off);
    if (l == 0) redB[d][w] = p;
  }
  __syncthreads();
  if (t < DPER) {
    float dot = redB[t][0] + redB[t][1] + redB[t][2] + redB[t][3];
    intra[m * DPER + t] = rr + c2v - 2.0f * dot;
  }
}

// ---------------- Kernel D: variance -> var_norm ----------------
__global__ __launch_bounds__(256) void k_var(const float* __restrict__ intra,
                                             float* __restrict__ vn) {
  const int t = threadIdx.x;
  float s = 0.f;
  for (int i = t; i < NSAMP; i += 256) s += intra[i];
  __shared__ float red[4];
  #pragma unroll
  for (int off = 32; off > 0; off >>= 1) s += __shfl_down(s, off);
  if ((t & 63) == 0) red[t >> 6] = s;
  __syncthreads();
  if (t == 0) {
    float tot = red[0] + red[1] + red[2] + red[3];
    float var = tot / (float)(NSAMP - 1);
    vn[0] = -1.0f / (2.0f * var * var);
  }
}

// ---------------- Kernel E: f16 MFMA GEMM (m97 template) + epilogue ----------
// 128x128x32 tile, 4 waves (2x2), wave tile 64x64, global_load_lds staging,
// XOR chunk swizzle. Grid 512 = 128 rowblks x 4 colblks, XCD-swizzled.
__global__ __launch_bounds__(256, 3) void k_gemm(
    const ushort* __restrict__ Af16, const ushort* __restrict__ Bf16,
    const float* __restrict__ c2, const float* __restrict__ r2,
    const float* __restrict__ vnp, const int* __restrict__ ccls,
    const int* __restrict__ target,
    float* __restrict__ den_p, float* __restrict__ minv_p,
    float* __restrict__ minv2_p, float* __restrict__ minc_p) {
  __shared__ ushort As[GBM * GBK];   // 8 KiB
  __shared__ ushort Bs[GBN * GBK];   // 8 KiB
  const int t = threadIdx.x;
  const int l = t & 63, w = t >> 6;
  const int wg = (blockIdx.x & 7) * 64 + (blockIdx.x >> 3);  // bijective (512%8==0)
  const int rowblk = wg >> 2, colblk = wg & 3;
  const int row0 = rowblk * GBM, c0 = colblk * GBN;
  const int wr = w >> 1, wc = w & 1;

  const int sR = l >> 2;
  const int sg = (l & 3) ^ (sR & 3);      // pre-swizzled source chunk
  const ushort* srcA0 = Af16 + (size_t)(row0 + w * 32 + sR) * NFEAT + sg * 8;
  const ushort* srcA1 = srcA0 + 16 * NFEAT;
  const ushort* srcB0 = Bf16 + (size_t)(c0 + w * 32 + sR) * NFEAT + sg * 8;
  const ushort* srcB1 = srcB0 + 16 * NFEAT;
  ushort* ldsA0 = As + w * 32 * GBK;
  ushort* ldsA1 = ldsA0 + 16 * GBK;
  ushort* ldsB0 = Bs + w * 32 * GBK;
  ushort* ldsB1 = ldsB0 + 16 * GBK;

  const int fr = l & 15, fq = l >> 4;
  const int ch = ((fq ^ (fr & 3)) * 8);   // swizzled chunk offset (ushorts)

  f32x4 acc[4][4];
  #pragma unroll
  for (int i = 0; i < 4; ++i)
    #pragma unroll
    for (int j = 0; j < 4; ++j) acc[i][j] = (f32x4){0.f, 0.f, 0.f, 0.f};

  for (int ks = 0; ks < NFEAT / GBK; ++ks) {
    __syncthreads();
    gload16(srcA0, ldsA0); gload16(srcA1, ldsA1);
    gload16(srcB0, ldsB0); gload16(srcB1, ldsB1);
    srcA0 += GBK; srcA1 += GBK; srcB0 += GBK; srcB1 += GBK;
    __syncthreads();
    f16x8 a[4], b[4];
    #pragma unroll
    for (int i = 0; i < 4; ++i)
      a[i] = *(const f16x8*)&As[(wr * 64 + i * 16 + fr) * GBK + ch];
    #pragma unroll
    for (int j = 0; j < 4; ++j)
      b[j] = *(const f16x8*)&Bs[(wc * 64 + j * 16 + fr) * GBK + ch];
    #pragma unroll
    for (int i = 0; i < 4; ++i)
      #pragma unroll
      for (int j = 0; j < 4; ++j)
        acc[i][j] = __builtin_amdgcn_mfma_f32_16x16x32_f16(a[i], b[j], acc[i][j], 0, 0, 0);
  }

  // ---- fused epilogue: per 64-col chunk: den, best, second-best, argmin ----
  const float vn = vnp[0];
  float c2j[4]; int clsj[4];
  #pragma unroll
  for (int j = 0; j < 4; ++j) {
    const int c = c0 + wc * 64 + j * 16 + fr;
    c2j[j] = c2[c];
    clsj[j] = ccls[c];
  }
  const int colchunk = colblk * 2 + wc;
  #pragma unroll
  for (int i = 0; i < 4; ++i) {
    const int rbase = row0 + wr * 64 + i * 16 + fq * 4;
    float r2v[4]; int tg[4];
    #pragma unroll
    for (int v = 0; v < 4; ++v) { r2v[v] = r2[rbase + v]; tg[v] = target[rbase + v]; }
    #pragma unroll
    for (int v = 0; v < 4; ++v) {
      float den = 0.f, bv = 3.4e38f, bv2 = 3.4e38f;
      int bc = 1 << 30;
      #pragma unroll
      for (int j = 0; j < 4; ++j) {
        const float cost = r2v[v] + c2j[j] - 2.0f * acc[i][j][v];
        if (clsj[j] != tg[v]) den += __expf(vn * cost);
        if (cost < bv) { bv2 = bv; bv = cost; bc = c0 + wc * 64 + j * 16 + fr; }
        else if (cost < bv2) { bv2 = cost; }
      }
      #pragma unroll
      for (int off = 1; off < 16; off <<= 1) {
        den += __shfl_xor(den, off);
        const float ov = __shfl_xor(bv, off);
        const float ov2 = __shfl_xor(bv2, off);
        const int oc = __shfl_xor(bc, off);
        const float nb2 = fminf(fminf(bv2, ov2), fmaxf(bv, ov));
        if (ov < bv || (ov == bv && oc < bc)) { bv = ov; bc = oc; }
        bv2 = nb2;
      }
      if (fr == 0) {
        const int idx = colchunk * NSAMP + rbase + v;
        den_p[idx] = den;
        minv_p[idx] = bv;
        minv2_p[idx] = bv2;
        minc_p[idx] = (float)bc;
      }
    }
  }
}

// ---------------- Kernel F2: combine partials; worklist append ----------------
__global__ __launch_bounds__(256) void k_fin2(const float* __restrict__ den_p,
                                              const float* __restrict__ minv_p,
                                              const float* __restrict__ minv2_p,
                                              const float* __restrict__ minc_p,
                                              const float* __restrict__ intra,
                                              const float* __restrict__ vnp,
                                              float* __restrict__ losses,
                                              float* __restrict__ preds,
                                              int* __restrict__ wl,
                                              int* __restrict__ wcount) {
  const int row = blockIdx.x * 256 + threadIdx.x;
  float den = 0.f, bv = 3.4e38f, bv2 = 3.4e38f, bc = 0.f;
  #pragma unroll
  for (int k = 0; k < NCHUNK; ++k) {
    den += den_p[k * NSAMP + row];
    const float v = minv_p[k * NSAMP + row];
    const float v2 = minv2_p[k * NSAMP + row];
    const float c = minc_p[k * NSAMP + row];
    const float nb2 = fminf(fminf(bv2, v2), fmaxf(bv, v));
    if (v < bv) { bv = v; bc = c; }   // ascending chunk -> first (lowest col) wins ties
    bv2 = nb2;
  }
  const float num = expf(vnp[0] * intra[row] - ALPHA_C);
  const float ratio = num / (den + EPS_C) + EPS_C;
  float loss = -logf(ratio);
  losses[row] = loss > 0.f ? loss : 0.f;
  preds[row] = bc;
  if (bv2 - bv < MARGIN_C) {
    int i = atomicAdd(wcount, 1);
    wl[i] = row;
  }
}

// ---------------- Kernel G: exact fp32 argmin fixup (worklist) -------------
__global__ __launch_bounds__(256) void k_fix(const float* __restrict__ inp,
                                             const float* __restrict__ means,
                                             const float* __restrict__ c2,
                                             const float* __restrict__ r2,
                                             const int* __restrict__ wl,
                                             const int* __restrict__ wcount,
                                             float* __restrict__ preds) {
  __shared__ float rbuf[NFEAT];
  __shared__ float redv[4];
  __shared__ int redc[4];
  const int t = threadIdx.x;
  const int l = t & 63, w = t >> 6;
  const int cnt = *wcount;
  for (int i = blockIdx.x; i < cnt; i += gridDim.x) {
    const int row = wl[i];
    for (int k = t; k < NFEAT; k += 256) rbuf[k] = inp[(size_t)row * NFEAT + k];
    __syncthreads();
    const float r2v = r2[row];
    float bv = 3.4e38f; int bc = 1 << 30;
    for (int c = t; c < NCLUST; c += 256) {
      const float4* mp = (const float4*)(means + (size_t)c * NFEAT);
      float dot = 0.f;
      #pragma unroll 8
      for (int k = 0; k < NFEAT / 4; ++k) {
        const float4 m4 = mp[k];
        dot += rbuf[k * 4 + 0] * m4.x + rbuf[k * 4 + 1] * m4.y +
               rbuf[k * 4 + 2] * m4.z + rbuf[k * 4 + 3] * m4.w;
      }
      const float cost = r2v + c2[c] - 2.0f * dot;
      if (cost < bv) { bv = cost; bc = c; }   // ascending c: strict < keeps first
    }
    #pragma unroll
    for (int off = 1; off < 64; off <<= 1) {
      const float ov = __shfl_xor(bv, off);
      const int oc = __shfl_xor(bc, off);
      if (ov < bv || (ov == bv && oc < bc)) { bv = ov; bc = oc; }
    }
    if (l == 0) { redv[w] = bv; redc[w] = bc; }
    __syncthreads();
    if (t == 0) {
      float fbv = redv[0]; int fbc = redc[0];
      #pragma unroll
      for (int k = 1; k < 4; ++k) {
        if (redv[k] < fbv || (redv[k] == fbv && redc[k] < fbc)) { fbv = redv[k]; fbc = redc[k]; }
      }
      preds[row] = (float)fbc;
    }
    __syncthreads();
  }
}

// ---------------- Kernel F: total_loss + acc (deterministic) ----------------
__global__ __launch_bounds__(256) void k_final(const float* __restrict__ losses,
                                               const float* __restrict__ preds,
                                               float* __restrict__ out) {
  const int t = threadIdx.x;
  float s = 0.f, cnt = 0.f;
  for (int i = t; i < NSAMP; i += 256) {
    s += losses[i];
    int p = (int)preds[i];
    cnt += (p == (i >> 5)) ? 1.f : 0.f;
  }
  __shared__ float redS[4], redC[4];
  #pragma unroll
  for (int off = 32; off > 0; off >>= 1) {
    s += __shfl_down(s, off);
    cnt += __shfl_down(cnt, off);
  }
  if ((t & 63) == 0) { redS[t >> 6] = s; redC[t >> 6] = cnt; }
  __syncthreads();
  if (t == 0) {
    out[0] = (redS[0] + redS[1] + redS[2] + redS[3]) / (float)NSAMP;
    out[1 + 2 * NSAMP] = (redC[0] + redC[1] + redC[2] + redC[3]) / (float)NSAMP;
  }
}

extern "C" void kernel_launch(void* const* d_in, const int* in_sizes, int n_in,
                              void* d_out, int out_size, void* d_ws, size_t ws_size,
                              hipStream_t stream) {
  const float* inp = (const float*)d_in[0];
  const int* target = (const int*)d_in[1];
  float* out = (float*)d_out;

  ushort* Af16 = (ushort*)d_ws;                        // 16384*1024 f16 (32 MiB)
  ushort* Bf16 = Af16 + (size_t)NSAMP * NFEAT;         // 512*1024 f16 (1 MiB)
  float* means = (float*)(Bf16 + (size_t)NCLUST * NFEAT);  // 512*1024 f32
  float* c2 = means + (size_t)NCLUST * NFEAT;          // 512
  float* r2 = c2 + NCLUST;                             // 16384
  float* intra = r2 + NSAMP;                           // 16384
  float* vn = intra + NSAMP;                           // 1
  int* ccls = (int*)(vn + 1);                          // 512
  float* den_p = (float*)(ccls + NCLUST);              // 8*16384
  float* minv_p = den_p + NCHUNK * NSAMP;              // 8*16384
  float* minv2_p = minv_p + NCHUNK * NSAMP;            // 8*16384
  float* minc_p = minv2_p + NCHUNK * NSAMP;            // 8*16384
  int* wl = (int*)(minc_p + NCHUNK * NSAMP);           // 16384
  int* wcount = wl + NSAMP;                            // 1

  float* losses = out + 1;
  float* preds = out + 1 + NSAMP;

  hipLaunchKernelGGL(k_pre, dim3(NCLUST), dim3(256), 0, stream,
                     inp, target, means, Bf16, Af16, c2, r2, intra, ccls, wcount);
  hipLaunchKernelGGL(k_var, dim3(1), dim3(256), 0, stream, intra, vn);
  hipLaunchKernelGGL(k_gemm, dim3(512), dim3(256), 0, stream,
                     Af16, Bf16, c2, r2, vn, ccls, target,
                     den_p, minv_p, minv2_p, minc_p);
  hipLaunchKernelGGL(k_fin2, dim3(NSAMP / 256), dim3(256), 0, stream,
                     den_p, minv_p, minv2_p, minc_p, intra, vn, losses, preds,
                     wl, wcount);
  hipLaunchKernelGGL(k_fix, dim3(128), dim3(256), 0, stream,
                     inp, means, c2, r2, wl, wcount, preds);
  hipLaunchKernelGGL(k_final, dim3(1), dim3(256), 0, stream, losses, preds, out);
}